// Round 7
// baseline (299.813 us; speedup 1.0000x reference)
//
#include <hip/hip_runtime.h>
#include <hip/hip_bf16.h>

#define NB 4
#define NS 2048
#define ND 1024
#define NH 16
#define NDH 64
#define E_ 8388608   // NB*NS*ND
#define W_ 1048576   // ND*ND

typedef __attribute__((ext_vector_type(8))) __bf16 bf16x8;
typedef __attribute__((ext_vector_type(4))) float f32x4;
typedef __attribute__((ext_vector_type(16))) float f32x16;
typedef unsigned short us16;
typedef unsigned int u32;

__device__ __forceinline__ unsigned short f2bf(float f) {
  union { float f; unsigned u; } v; v.f = f;
  unsigned r = v.u + 0x7FFFu + ((v.u >> 16) & 1u);
  return (unsigned short)(r >> 16);
}

typedef const __attribute__((address_space(1))) unsigned int* gas_t;
typedef __attribute__((address_space(3))) unsigned int* las_t;
__device__ __forceinline__ void gl2lds16(const void* g, void* l) {
  __builtin_amdgcn_global_load_lds((gas_t)g, (las_t)l, 16, 0, 0);
}

// ---------------------------------------------------------------------------
// fp32 -> bf16 conversion pass
// ---------------------------------------------------------------------------
__global__ __launch_bounds__(256) void conv_bf16(
    const float* __restrict__ q, const float* __restrict__ k, const float* __restrict__ v,
    const float* __restrict__ wq, const float* __restrict__ wk, const float* __restrict__ wv,
    const float* __restrict__ wo,
    us16* __restrict__ qb, us16* __restrict__ kb, us16* __restrict__ vb,
    us16* __restrict__ wqb, us16* __restrict__ wkb, us16* __restrict__ wvb,
    us16* __restrict__ wob)
{
  int b = blockIdx.x;
  int seg, off;
  if (b < 24576) { seg = b >> 13; off = b & 8191; }
  else { b -= 24576; seg = 3 + (b >> 10); off = b & 1023; }
  const float* s; us16* d;
  switch (seg) {
    case 0: s = q;  d = qb;  break;
    case 1: s = k;  d = kb;  break;
    case 2: s = v;  d = vb;  break;
    case 3: s = wq; d = wqb; break;
    case 4: s = wk; d = wkb; break;
    case 5: s = wv; d = wvb; break;
    default: s = wo; d = wob; break;
  }
  size_t idx = ((size_t)off * 256 + threadIdx.x) * 4;
  float4 f = *(const float4*)(s + idx);
  ushort4 u;
  u.x = f2bf(f.x); u.y = f2bf(f.y); u.z = f2bf(f.z); u.w = f2bf(f.w);
  *(ushort4*)(d + idx) = u;
}

// ---------------------------------------------------------------------------
// Projection GEMM (bf16), R1-proven 2-barrier structure: Y = X @ W^T + bias.
// seg 0: Q plain [B,S,D] scaled; seg 1: K plain [B,S,D]; seg 2: V -> [B,H,DH,S].
// ---------------------------------------------------------------------------
__global__ __launch_bounds__(256, 3) void gemm_proj3(
    const us16* __restrict__ A0, const us16* __restrict__ A1, const us16* __restrict__ A2,
    const us16* __restrict__ W0, const us16* __restrict__ W1, const us16* __restrict__ W2,
    const float* __restrict__ b0, const float* __restrict__ b1, const float* __restrict__ b2,
    us16* __restrict__ o0, us16* __restrict__ o1, us16* __restrict__ o2,
    float qscale, int s0, int s1, int s2)
{
  const int seg = (blockIdx.z == 0) ? s0 : (blockIdx.z == 1) ? s1 : s2;
  const us16* A  = (blockIdx.z == 0) ? A0 : (blockIdx.z == 1) ? A1 : A2;
  const us16* Wt = (blockIdx.z == 0) ? W0 : (blockIdx.z == 1) ? W1 : W2;
  const float* bias = (blockIdx.z == 0) ? b0 : (blockIdx.z == 1) ? b1 : b2;
  us16* out = (blockIdx.z == 0) ? o0 : (blockIdx.z == 1) ? o1 : o2;
  const float scale = (seg == 0) ? qscale : 1.0f;

  __shared__ us16 As[128][64];
  __shared__ us16 Bs[128][64];
  const int tid = threadIdx.x;
  const int lane = tid & 63;
  const int w = tid >> 6;
  const int l15 = lane & 15, quad = lane >> 4;
  const int sw = l15 & 7;
  const int rowBase = blockIdx.x * 128, colBase = blockIdx.y * 128;
  const int srow = w * 32 + (lane >> 3);
  const int cu = (lane & 7) ^ ((lane >> 3) & 7);
  const us16* ga = A  + (size_t)(rowBase + srow) * ND + cu * 8;
  const us16* gb = Wt + (size_t)(colBase + srow) * ND + cu * 8;
  const int wr = (w >> 1) * 64, wc = (w & 1) * 64;

  f32x4 acc[4][4] = {};
  for (int kt = 0; kt < ND; kt += 64) {
    __syncthreads();
    #pragma unroll
    for (int c = 0; c < 4; ++c) {
      gl2lds16(ga + kt + c * 8 * ND, &As[w * 32 + c * 8][0]);
      gl2lds16(gb + kt + c * 8 * ND, &Bs[w * 32 + c * 8][0]);
    }
    __syncthreads();
    #pragma unroll
    for (int ks = 0; ks < 2; ++ks) {
      bf16x8 af[4], bfr[4];
      #pragma unroll
      for (int i = 0; i < 4; ++i)
        af[i]  = *(const bf16x8*)&As[wr + i * 16 + l15][((ks * 4 + quad) ^ sw) * 8];
      #pragma unroll
      for (int j = 0; j < 4; ++j)
        bfr[j] = *(const bf16x8*)&Bs[wc + j * 16 + l15][((ks * 4 + quad) ^ sw) * 8];
      #pragma unroll
      for (int i = 0; i < 4; ++i)
        #pragma unroll
        for (int j = 0; j < 4; ++j)
          acc[i][j] = __builtin_amdgcn_mfma_f32_16x16x32_bf16(af[i], bfr[j], acc[i][j], 0, 0, 0);
    }
  }

  if (seg < 2) {
    #pragma unroll
    for (int i = 0; i < 4; ++i) {
      #pragma unroll
      for (int j = 0; j < 4; ++j) {
        int colg = colBase + wc + j * 16 + l15;
        float bval = bias[colg];
        #pragma unroll
        for (int r = 0; r < 4; ++r) {
          int rowg = rowBase + wr + i * 16 + quad * 4 + r;
          out[(size_t)rowg * ND + colg] = f2bf((acc[i][j][r] + bval) * scale);
        }
      }
    }
  } else {
    #pragma unroll
    for (int i = 0; i < 4; ++i) {
      #pragma unroll
      for (int j = 0; j < 4; ++j) {
        int colg = colBase + wc + j * 16 + l15;
        float bval = bias[colg];
        int h_ = colg >> 6, d_ = colg & 63;
        int rowg0 = rowBase + wr + i * 16 + quad * 4;
        int b_ = rowg0 >> 11, sr0 = rowg0 & (NS - 1);
        ushort4 vv;
        vv.x = f2bf(acc[i][j][0] + bval);
        vv.y = f2bf(acc[i][j][1] + bval);
        vv.z = f2bf(acc[i][j][2] + bval);
        vv.w = f2bf(acc[i][j][3] + bval);
        *(ushort4*)(out + ((size_t)(b_ * NH + h_) * NDH + d_) * NS + sr0) = vv;
      }
    }
  }
}

// ---------------------------------------------------------------------------
// Flash attention R7 (= R6 with the permlane operand-order fix): 256-q tile,
// 8 waves x 32 q, KVBLK=128, 32x32x16 MFMA, in-register P (T12), Q in regs,
// VALU denominator. LDS = K 32K + V^T 32K + inv 1K = 65KB. Grid 256,
// pass-pairing (pr, 7-pr) -> 18 key-tiles per block, uniform.
// QK: mfma(A=K 32kx16d, B=Q 16dx32q) -> C col=q(lane&31), row=k(reg map).
// T12: v_permlane32_swap_b32 dst,src swaps dst[32:63] <-> src[0:31] (S1).
// With dst=m[2j(lo-keys)], src=m[2j+? ...]: correct pairing is dst=m0,src=m2:
// new_m0 = A-word0 (hi0: own {0,1}; hi1: partner {8,9}),
// new_m2 = A-word2 (hi0: partner {4,5}; hi1: own {12,13}).  (HK recipe order.)
// ---------------------------------------------------------------------------
__global__ __launch_bounds__(512, 1) void attn(
    const us16* __restrict__ Qh, const us16* __restrict__ Kh,
    const us16* __restrict__ Vht, us16* __restrict__ ctx)
{
  __shared__ us16 Ks[2][128][64];    // [k][d-slot], slot s holds global chunk s^(k&7)
  __shared__ us16 Vts[2][64][128];   // [d][k-slot], slot s holds global chunk (s&8)|((s&7)^(d&7))
  __shared__ float invL[8][32];      // per-wave denominator broadcast

  const int bh = blockIdx.x & 63;    // %8 XCD round-robin: same head -> same XCD
  const int pr = blockIdx.x >> 6;    // 0..3
  const int b_ = bh >> 4, h_ = bh & 15;
  const int tid = threadIdx.x, lane = tid & 63, w = tid >> 6;  // 8 waves
  const int l31 = lane & 31;
  const int hi = lane >> 5;
  const int lr8 = lane >> 3;
  const int cu = (lane & 7) ^ (lr8 & 7);
  // V staging lane map (4 rows x 16 slots per 1KB chunk)
  const int vr = lane >> 4;
  const int vs = lane & 15;
  const int cs0 = (vs & 8) | ((vs & 7) ^ vr);
  const int cs1 = (vs & 8) | ((vs & 7) ^ (vr | 4));

  const us16* gk  = Kh  + ((size_t)b_ * NS + w * 16 + lr8) * ND + h_ * NDH + cu * 8;
  const us16* gv0 = Vht + ((size_t)bh * NDH + w * 8 + vr) * NS + cs0 * 8;
  const us16* gv1 = Vht + ((size_t)bh * NDH + w * 8 + 4 + vr) * NS + cs1 * 8;

  for (int pass = 0; pass < 2; ++pass) {
    const int tq = pass ? (7 - pr) : pr;
    const int qb0 = tq * 256;
    const int nt = (tq + 1) * 2;       // 128-key tiles (causal)
    const int qw = qb0 + w * 32;       // wave's first q-row
    const int qg = qw + l31;           // lane's q-row

    // Q -> registers (B-frags, 16dx32q per d-step): col q = lane&31,
    // row d = ds*16 + hi*8 + e. Direct from global (L2-hot).
    bf16x8 bq[4];
    {
      const us16* gq = Qh + ((size_t)b_ * NS + qg) * ND + h_ * NDH + hi * 8;
      #pragma unroll
      for (int ds = 0; ds < 4; ++ds)
        bq[ds] = *(const bf16x8*)(gq + ds * 16);
    }

    __syncthreads();   // previous pass fully done with K/V LDS
    // prefetch tile 0 -> buffer 0
    gl2lds16(gk,            &Ks[0][w * 16][0]);
    gl2lds16(gk + 8 * ND,   &Ks[0][w * 16 + 8][0]);
    gl2lds16(gv0,           &Vts[0][w * 8][0]);
    gl2lds16(gv1,           &Vts[0][w * 8 + 4][0]);

    f32x16 o0 = {}, o1 = {};
    float o_l = 0.f;

    for (int it = 0; it < nt; ++it) {
      const int kb = it * 128;
      const int cur = it & 1;
      __syncthreads();   // tile `it` landed (vmcnt drained); prev compute done
      if (it + 1 < nt) {
        const int nxt = cur ^ 1;
        const int kn = kb + 128;
        gl2lds16(gk + (size_t)kn * ND,        &Ks[nxt][w * 16][0]);
        gl2lds16(gk + (size_t)(kn + 8) * ND,  &Ks[nxt][w * 16 + 8][0]);
        gl2lds16(gv0 + kn,                    &Vts[nxt][w * 8][0]);
        gl2lds16(gv1 + kn,                    &Vts[nxt][w * 8 + 4][0]);
      }
      #pragma unroll
      for (int kb4 = 0; kb4 < 4; ++kb4) {
        const int keyb0 = kb + kb4 * 32;
        if (keyb0 > qw + 31) continue;       // wave-uniform diagonal skip
        const bool full = (keyb0 + 31 <= qw);

        // QK^T: A = K (32k x 16d), accumulate over 4 d-steps
        f32x16 c = {};
        __builtin_amdgcn_s_setprio(1);
        #pragma unroll
        for (int ds = 0; ds < 4; ++ds) {
          bf16x8 ak = *(const bf16x8*)
              &Ks[cur][kb4 * 32 + l31][(((ds * 2 + hi) ^ (l31 & 7)) * 8)];
          c = __builtin_amdgcn_mfma_f32_32x32x16_bf16(ak, bq[ds], c, 0, 0, 0);
        }
        __builtin_amdgcn_s_setprio(0);

        // mask + exp2 (k-row for reg r: (r&3)+8*(r>>2)+4*hi)
        float p[16];
        if (full) {
          #pragma unroll
          for (int r = 0; r < 16; ++r)
            p[r] = __builtin_amdgcn_exp2f(c[r]);
        } else {
          #pragma unroll
          for (int r = 0; r < 16; ++r) {
            int kg = keyb0 + (r & 3) + 8 * (r >> 2) + 4 * hi;
            p[r] = (kg <= qg) ? __builtin_amdgcn_exp2f(c[r]) : 0.f;
          }
        }
        // denominator partial (this half's 16 k's for q = l31)
        {
          float s0 = (p[0] + p[1]) + (p[2] + p[3]);
          float s1 = (p[4] + p[5]) + (p[6] + p[7]);
          float s2 = (p[8] + p[9]) + (p[10] + p[11]);
          float s3 = (p[12] + p[13]) + (p[14] + p[15]);
          o_l += (s0 + s1) + (s2 + s3);
        }
        // pack to bf16 pairs: m[j] = {bf16(p[2j]), bf16(p[2j+1])}
        u32 m[8];
        #pragma unroll
        for (int j = 0; j < 8; ++j)
          asm("v_cvt_pk_bf16_f32 %0, %1, %2" : "=v"(m[j]) : "v"(p[2 * j]), "v"(p[2 * j + 1]));
        // T12 redistribution, S1 semantics: dst = lower-key word, src = +2 word
        asm volatile("v_permlane32_swap_b32 %0, %1" : "+v"(m[0]), "+v"(m[2]));
        asm volatile("v_permlane32_swap_b32 %0, %1" : "+v"(m[1]), "+v"(m[3]));
        asm volatile("v_permlane32_swap_b32 %0, %1" : "+v"(m[4]), "+v"(m[6]));
        asm volatile("v_permlane32_swap_b32 %0, %1" : "+v"(m[5]), "+v"(m[7]));
        union { u32 u[4]; bf16x8 v; } pa0, pa1;
        pa0.u[0] = m[0]; pa0.u[1] = m[1]; pa0.u[2] = m[2]; pa0.u[3] = m[3];
        pa1.u[0] = m[4]; pa1.u[1] = m[5]; pa1.u[2] = m[6]; pa1.u[3] = m[7];

        // PV: B = V (16k x 32d); k-chunk g = kb4*4 + t*2 + hi
        const int sw7 = l31 & 7;
        const int g0 = kb4 * 4 + hi;       // t=0
        const int g1 = kb4 * 4 + 2 + hi;   // t=1
        const int s00 = (g0 & 8) | ((g0 & 7) ^ sw7);
        const int s01 = (g1 & 8) | ((g1 & 7) ^ sw7);
        bf16x8 bv00 = *(const bf16x8*)&Vts[cur][l31][s00 * 8];
        bf16x8 bv01 = *(const bf16x8*)&Vts[cur][l31][s01 * 8];
        bf16x8 bv10 = *(const bf16x8*)&Vts[cur][32 + l31][s00 * 8];
        bf16x8 bv11 = *(const bf16x8*)&Vts[cur][32 + l31][s01 * 8];
        __builtin_amdgcn_s_setprio(1);
        o0 = __builtin_amdgcn_mfma_f32_32x32x16_bf16(pa0.v, bv00, o0, 0, 0, 0);
        o0 = __builtin_amdgcn_mfma_f32_32x32x16_bf16(pa1.v, bv01, o0, 0, 0, 0);
        o1 = __builtin_amdgcn_mfma_f32_32x32x16_bf16(pa0.v, bv10, o1, 0, 0, 0);
        o1 = __builtin_amdgcn_mfma_f32_32x32x16_bf16(pa1.v, bv11, o1, 0, 0, 0);
        __builtin_amdgcn_s_setprio(0);
      }
    }

    // epilogue: merge denominator halves, broadcast inv, write ctx
    {
      float a = o_l, b = o_l;
      asm volatile("v_permlane32_swap_b32 %0, %1" : "+v"(a), "+v"(b));
      float tot = a + b;                    // lanes<32: own+partner; >=32: partner+own
      float inv = __builtin_amdgcn_rcpf(tot);
      if (lane < 32) invL[w][l31] = inv;
      #pragma unroll
      for (int r = 0; r < 16; ++r) {
        int qrow = (r & 3) + 8 * (r >> 2) + 4 * hi;
        float iv = invL[w][qrow];
        us16* dst = ctx + ((size_t)b_ * NS + qb0 + w * 32 + qrow) * ND + h_ * NDH + l31;
        dst[0]  = f2bf(o0[r] * iv);
        dst[32] = f2bf(o1[r] * iv);
      }
    }
  }
}

// ---------------------------------------------------------------------------
// Output projection (R1-proven): out = ctx(bf16) @ wo^T(bf16) + bo, fp32
// ---------------------------------------------------------------------------
__global__ __launch_bounds__(256, 3) void gemm_out(
    const us16* __restrict__ A, const us16* __restrict__ Wt,
    const float* __restrict__ bias, float* __restrict__ out)
{
  __shared__ us16 As[128][64];
  __shared__ us16 Bs[128][64];
  const int tid = threadIdx.x;
  const int lane = tid & 63;
  const int w = tid >> 6;
  const int l15 = lane & 15, quad = lane >> 4;
  const int sw = l15 & 7;
  const int rowBase = blockIdx.x * 128, colBase = blockIdx.y * 128;
  const int srow = w * 32 + (lane >> 3);
  const int cu = (lane & 7) ^ ((lane >> 3) & 7);
  const us16* ga = A  + (size_t)(rowBase + srow) * ND + cu * 8;
  const us16* gb = Wt + (size_t)(colBase + srow) * ND + cu * 8;
  const int wr = (w >> 1) * 64, wc = (w & 1) * 64;

  f32x4 acc[4][4] = {};
  for (int kt = 0; kt < ND; kt += 64) {
    __syncthreads();
    #pragma unroll
    for (int c = 0; c < 4; ++c) {
      gl2lds16(ga + kt + c * 8 * ND, &As[w * 32 + c * 8][0]);
      gl2lds16(gb + kt + c * 8 * ND, &Bs[w * 32 + c * 8][0]);
    }
    __syncthreads();
    #pragma unroll
    for (int ks = 0; ks < 2; ++ks) {
      bf16x8 af[4], bfr[4];
      #pragma unroll
      for (int i = 0; i < 4; ++i)
        af[i]  = *(const bf16x8*)&As[wr + i * 16 + l15][((ks * 4 + quad) ^ sw) * 8];
      #pragma unroll
      for (int j = 0; j < 4; ++j)
        bfr[j] = *(const bf16x8*)&Bs[wc + j * 16 + l15][((ks * 4 + quad) ^ sw) * 8];
      #pragma unroll
      for (int i = 0; i < 4; ++i)
        #pragma unroll
        for (int j = 0; j < 4; ++j)
          acc[i][j] = __builtin_amdgcn_mfma_f32_16x16x32_bf16(af[i], bfr[j], acc[i][j], 0, 0, 0);
    }
  }

  #pragma unroll
  for (int i = 0; i < 4; ++i) {
    #pragma unroll
    for (int j = 0; j < 4; ++j) {
      int colg = colBase + wc + j * 16 + l15;
      float bval = bias[colg];
      #pragma unroll
      for (int r = 0; r < 4; ++r) {
        int rowg = rowBase + wr + i * 16 + quad * 4 + r;
        out[(size_t)rowg * ND + colg] = acc[i][j][r] + bval;
      }
    }
  }
}

extern "C" void kernel_launch(void* const* d_in, const int* in_sizes, int n_in,
                              void* d_out, int out_size, void* d_ws, size_t ws_size,
                              hipStream_t stream) {
  const float* q  = (const float*)d_in[0];
  const float* k  = (const float*)d_in[1];
  const float* v  = (const float*)d_in[2];
  // d_in[3] = mask (causal by construction)
  const float* wq = (const float*)d_in[4];
  const float* bq_ = (const float*)d_in[5];
  const float* wk = (const float*)d_in[6];
  const float* bk_ = (const float*)d_in[7];
  const float* wv = (const float*)d_in[8];
  const float* bv_ = (const float*)d_in[9];
  const float* wo = (const float*)d_in[10];
  const float* bo_ = (const float*)d_in[11];

  us16* ws = (us16*)d_ws;
  us16* qb  = ws;
  us16* kb  = ws + (size_t)E_;
  us16* vb  = ws + (size_t)2 * E_;     // later reused as ctx
  us16* wqb = ws + (size_t)3 * E_;
  us16* wkb = wqb + W_;
  us16* wvb = wkb + W_;
  us16* wob = wvb + W_;
  us16* KhF = wob + W_;                // fused-path K output (fresh region)
  us16* ctx = vb;
  us16* Vht = (us16*)d_out;            // d_out scratch: dead before gemm_out
  us16* Qh  = (us16*)d_out + (size_t)E_;

  const float qscale = 0.125f * 1.44269504088896340736f;  // 1/sqrt(DH)*log2(e)
  const bool fused = ws_size >= ((size_t)4 * E_ + 4 * W_) * 2;

  conv_bf16<<<28672, 256, 0, stream>>>(q, k, v, wq, wk, wv, wo,
                                       qb, kb, vb, wqb, wkb, wvb, wob);
  if (fused) {
    gemm_proj3<<<dim3(64, 8, 3), 256, 0, stream>>>(
        qb, kb, vb, wqb, wkb, wvb, bq_, bk_, bv_, Qh, KhF, Vht, qscale, 0, 1, 2);
    attn<<<256, 512, 0, stream>>>(Qh, KhF, Vht, ctx);
  } else {
    gemm_proj3<<<dim3(64, 8, 2), 256, 0, stream>>>(
        qb, vb, vb, wqb, wvb, wvb, bq_, bv_, bv_, Qh, Vht, Vht, qscale, 0, 2, 2);
    gemm_proj3<<<dim3(64, 8, 1), 256, 0, stream>>>(
        kb, kb, kb, wkb, wkb, wkb, bk_, bk_, bk_, qb, qb, qb, qscale, 1, 1, 1);
    attn<<<256, 512, 0, stream>>>(Qh, qb, Vht, ctx);
  }
  gemm_out<<<dim3(64, 8), 256, 0, stream>>>(ctx, wob, bo_, (float*)d_out);
}